// Round 3
// 513.301 us; speedup vs baseline: 1.0800x; 1.0800x over previous
//
#include <hip/hip_runtime.h>

#define NTHR 256

typedef __bf16 bf16x8 __attribute__((ext_vector_type(8)));
typedef float  f32x4  __attribute__((ext_vector_type(4)));

__device__ __forceinline__ unsigned short f2bf(float f) {
  unsigned int u = __float_as_uint(f);
  return (unsigned short)((u + 0x7fffu + ((u >> 16) & 1u)) >> 16);  // RNE
}
__device__ __forceinline__ bf16x8 asbf(uint4 u) { return __builtin_bit_cast(bf16x8, u); }
__device__ __forceinline__ float sigf(float xv) { return 1.0f / (1.0f + __expf(-xv)); }

// --- cross-XCD primitives (all proven by the multi-launch kernel) ---
// reads: relaxed agent-scope atomic load (L1/L2-bypassing to coherence point)
template <typename T>
__device__ __forceinline__ T ald(const T* p) {
  return __hip_atomic_load(p, __ATOMIC_RELAXED, __HIP_MEMORY_SCOPE_AGENT);
}
// publishes: relaxed agent-scope atomic EXCHANGE (RMW -> lands at coherence
// point like unsafeAtomicAdd did; value-ignored). No cache-wide fences.
template <typename T>
__device__ __forceinline__ void xst(T* p, T v) {
  (void)__hip_atomic_exchange(p, v, __ATOMIC_RELAXED, __HIP_MEMORY_SCOPE_AGENT);
}
__device__ __forceinline__ unsigned long long pkf2(float a, float b) {
  float2 f = make_float2(a, b);
  return __builtin_bit_cast(unsigned long long, f);
}

// ws layout (bytes):
//   OUTB bf16 [2][32][1024]        parity ping-pong of cell input     131072
//   HBB  bf16 [2][2][32][1024]     [t-parity][layer] h for GEMM       262144
//   HST  f32  [2][32][1024]        fp32 h state                       262144
//   CST  f32  [2][32][1024]        fp32 c state                       262144
//   PS   f32  [64][4][4][16][32]   [g][kb][gate][c][m] partials      2097152
//   FLG  int  [32][64]             per-cell split-K completion flags     8192
//   CNT  int  [32]                 per-cell grid-barrier counters         128
//   BCB  f32  [2][4096]            combined bias                        32768
//   SSE  f32
#define WS_OUTB 0
#define WS_HBB  131072
#define WS_HST  (WS_HBB + 262144)
#define WS_CST  (WS_HST + 262144)
#define WS_PS   (WS_CST + 262144)
#define WS_FLG  (WS_PS + 2097152)
#define WS_CNT  (WS_FLG + 8192)
#define WS_BCB  (WS_CNT + 128)
#define WS_SSE  (WS_BCB + 32768)

// ---------------- prep: state init only ----------------
__global__ void prep_kernel(const float* __restrict__ x, const float* __restrict__ h0,
                            const float* __restrict__ c0,
                            const float* __restrict__ bih, const float* __restrict__ bhh,
                            unsigned char* __restrict__ ws)
{
  unsigned short* outb = (unsigned short*)(ws + WS_OUTB);
  unsigned short* hbb  = (unsigned short*)(ws + WS_HBB);
  float* hst = (float*)(ws + WS_HST);
  float* cst = (float*)(ws + WS_CST);
  int*   flg = (int*)(ws + WS_FLG);
  int*   cnt = (int*)(ws + WS_CNT);
  float* bcb = (float*)(ws + WS_BCB);
  float* sse = (float*)(ws + WS_SSE);

  int gid = blockIdx.x * blockDim.x + threadIdx.x;
  int stride = gridDim.x * blockDim.x;

  for (int i = gid; i < 32768; i += stride) outb[i] = f2bf(x[i]);   // parity 0 = x
  for (int i = gid; i < 65536; i += stride) {
    float h = h0[i];
    hbb[i] = f2bf(h);      // t-parity 0, both layers
    hst[i] = h;
    cst[i] = c0[i];
  }
  for (int i = gid; i < 8192; i += stride) bcb[i] = bih[i] + bhh[i];
  for (int i = gid; i < 2048; i += stride) flg[i] = 0;
  if (gid < 32) cnt[gid] = 0;
  if (gid == 0) *sse = 0.0f;
}

// ---------------- one cell inside the persistent kernel ----------------
template <int L>
__device__ __forceinline__ void cell_step(
    int t, const uint4 (&wreg)[16],
    const float* __restrict__ hmask, const float* __restrict__ cmask,
    const float* __restrict__ labels, float* __restrict__ out,
    unsigned char* __restrict__ ws, unsigned short* As, int* lfp)
{
  const int tid = threadIdx.x, bid = blockIdx.x;
  const int g = bid >> 2, kb = bid & 3;
  const int lane = tid & 63, wid = tid >> 6, q = lane >> 4, m0 = lane & 15;
  const int ci = t * 2 + L;

  unsigned short* outb = (unsigned short*)(ws + WS_OUTB);
  unsigned short* hbb  = (unsigned short*)(ws + WS_HBB);
  float* hst = (float*)(ws + WS_HST);
  float* cst = (float*)(ws + WS_CST);
  float* Ps  = (float*)(ws + WS_PS);
  int*   flg = (int*)(ws + WS_FLG);
  int*   cnt = (int*)(ws + WS_CNT);
  const float* bcb = (const float*)(ws + WS_BCB);
  float* sse = (float*)(ws + WS_SSE);

  // pointwise geometry: 1 row (mr) x 2 adjacent cols (jg, jg+1) per thread
  const int mr = tid >> 3, c2 = tid & 7;
  const int jg = g * 16 + c2 * 2;

  // --- read-only prefetch (immutable inputs; plain cached loads; issued
  //     before the spin so HBM latency hides under it) ---
  const int mbase = ci * 32768 + mr * 1024 + jg;
  float2 hm = *(const float2*)&hmask[mbase];
  float2 cm = *(const float2*)&cmask[mbase];
  float2 lb = make_float2(0.f, 0.f);
  if (L == 1) lb = *(const float2*)&labels[(mr * 16 + t) * 1024 + jg];
  float2 bv[4];
#pragma unroll
  for (int gt = 0; gt < 4; ++gt)
    bv[gt] = *(const float2*)&bcb[L * 4096 + gt * 1024 + jg];  // immutable after prep

  // --- grid barrier on previous cell ---
  if (ci > 0) {
    if (tid == 0) {
      while (ald(&cnt[ci - 1]) < 64) __builtin_amdgcn_s_sleep(1);
    }
    __syncthreads();
  }

  // --- A staging: 32 rows x 512 bf16 slice, 4096 x 8B device-coherent loads ---
  // chunk u (0..4095): row = u>>7 (0..31), col4 = (u&127)*4 shorts
  const unsigned short* asrc = (kb < 2)
      ? (outb + L * 32768 + kb * 512)
      : (hbb + ((t & 1) * 2 + L) * 32768 + (kb - 2) * 512);
  unsigned long long av[16];
#pragma unroll
  for (int it = 0; it < 16; ++it) {
    const int u = it * 256 + tid, row = u >> 7, c4 = u & 127;
    av[it] = ald((const unsigned long long*)(asrc + row * 1024 + c4 * 4));
  }
  // fp32 state prefetch (device-coherent; written at cell ci-2)
  const int sidx = L * 32768 + mr * 1024 + jg;
  float cp0 = ald(&cst[sidx]), cp1 = ald(&cst[sidx + 1]);
  float hp0 = ald(&hst[sidx]), hp1 = ald(&hst[sidx + 1]);
#pragma unroll
  for (int it = 0; it < 16; ++it) {
    const int u = it * 256 + tid, row = u >> 7, c4 = u & 127;
    *(unsigned long long*)&As[row * 520 + c4 * 4] = av[it];
  }
  __syncthreads();

  // --- MFMA: B operand resident in registers, A from LDS ---
  f32x4 acc0 = {0.f, 0.f, 0.f, 0.f}, acc1 = {0.f, 0.f, 0.f, 0.f};
#pragma unroll
  for (int ks = 0; ks < 16; ++ks) {
    const int kl = ks * 32 + q * 8;
    bf16x8 a0 = asbf(*(const uint4*)&As[m0 * 520 + kl]);
    bf16x8 a1 = asbf(*(const uint4*)&As[(m0 + 16) * 520 + kl]);
    bf16x8 b  = asbf(wreg[ks]);
    acc0 = __builtin_amdgcn_mfma_f32_16x16x32_bf16(a0, b, acc0, 0, 0, 0);
    acc1 = __builtin_amdgcn_mfma_f32_16x16x32_bf16(a1, b, acc1, 0, 0, 0);
  }

  // --- split-K partials: disjoint slots, 8B exchange publishes ---
  // Ps[g][kb][gate][c=m0][m]; C/D frag: col=lane&15 (=c), row=q*4+i (=m, +16)
  float* pq = Ps + (size_t)(((g * 4 + kb) * 4 + wid) * 16 + m0) * 32;
  xst((unsigned long long*)(pq + q * 4),      pkf2(acc0[0], acc0[1]));
  xst((unsigned long long*)(pq + q * 4 + 2),  pkf2(acc0[2], acc0[3]));
  xst((unsigned long long*)(pq + q * 4 + 16), pkf2(acc1[0], acc1[1]));
  xst((unsigned long long*)(pq + q * 4 + 18), pkf2(acc1[2], acc1[3]));

  __syncthreads();                    // vmcnt(0): exchanges complete at coherence point
  if (tid == 0)
    *lfp = __hip_atomic_fetch_add(&flg[ci * 64 + g], 1, __ATOMIC_RELAXED, __HIP_MEMORY_SCOPE_AGENT);
  __syncthreads();
  if (*lfp != 3) return;              // not the last K-quarter of this group

  // --- pointwise (last-arriving block of this column group) ---
  const float* pbase = Ps + (size_t)g * 8192;   // [kb][gate][c][m]
  float gs0[4], gs1[4];
#pragma unroll
  for (int gt = 0; gt < 4; ++gt) {
    float s0 = bv[gt].x, s1 = bv[gt].y;
#pragma unroll
    for (int k2 = 0; k2 < 4; ++k2) {
      s0 += ald(pbase + k2 * 2048 + gt * 512 + (c2 * 2)     * 32 + mr);
      s1 += ald(pbase + k2 * 2048 + gt * 512 + (c2 * 2 + 1) * 32 + mr);
    }
    gs0[gt] = s0; gs1[gt] = s1;
  }

  float i0 = sigf(gs0[0]), f0 = sigf(gs0[1]), g0 = tanhf(gs0[2]), o0 = sigf(gs0[3]);
  float i1 = sigf(gs1[0]), f1 = sigf(gs1[1]), g1 = tanhf(gs1[2]), o1 = sigf(gs1[3]);
  float cc0 = f0 * cp0 + i0 * g0, cc1 = f1 * cp1 + i1 * g1;
  float hc0 = o0 * tanhf(cc0),    hc1 = o1 * tanhf(cc1);
  float hn0 = hm.x * hp0 + (1.0f - hm.x) * hc0;
  float hn1 = hm.y * hp1 + (1.0f - hm.y) * hc1;
  float cn0 = cm.x * cp0 + (1.0f - cm.x) * cc0;
  float cn1 = cm.y * cp1 + (1.0f - cm.y) * cc1;

  xst((unsigned long long*)&cst[sidx], pkf2(cn0, cn1));
  xst((unsigned long long*)&hst[sidx], pkf2(hn0, hn1));
  const unsigned int hb = (unsigned int)f2bf(hn0) | ((unsigned int)f2bf(hn1) << 16);
  xst((unsigned int*)&outb[(L ^ 1) * 32768 + mr * 1024 + jg], hb);
  xst((unsigned int*)&hbb[(((t + 1) & 1) * 2 + L) * 32768 + mr * 1024 + jg], hb);

  if (L == 1) {
    *(float2*)&out[(mr * 16 + t) * 1024 + jg] = make_float2(hn0, hn1);  // flushed at kernel end
    float d0 = hn0 - lb.x, d1 = hn1 - lb.y;
    float s = d0 * d0 + d1 * d1;
#pragma unroll
    for (int off = 32; off > 0; off >>= 1) s += __shfl_down(s, off);
    if (lane == 0) atomicAdd(sse, s);
  }

  __syncthreads();                    // vmcnt(0): pointwise publishes complete
  if (tid == 0)
    __hip_atomic_fetch_add(&cnt[ci], 1, __ATOMIC_RELAXED, __HIP_MEMORY_SCOPE_AGENT);
}

// ---------------- persistent kernel: weights in registers, 32 cells in-kernel ----
// grid = 256 blocks (1/CU resident by construction).
__global__ void __launch_bounds__(NTHR, 1)
lstm_kernel(const float* __restrict__ Wih, const float* __restrict__ Whh,
            const float* __restrict__ hmask, const float* __restrict__ cmask,
            const float* __restrict__ labels, float* __restrict__ out,
            unsigned char* __restrict__ ws)
{
  const int tid = threadIdx.x, bid = blockIdx.x;
  const int g = bid >> 2, kb = bid & 3;
  const int wid = tid >> 6, q = (tid & 63) >> 4, m0 = tid & 15;

  __shared__ __align__(16) unsigned short As[32 * 520];
  __shared__ int lf;

  // ---- one-time: fp32 weights -> bf16 registers, both layers (128 VGPRs) ----
  // row (layer l) = l*4096 + wid*1024 + g*16 + m0 ; K-concat col = kb*512 + q*8 + ks*32
  uint4 w0[16], w1[16];
  {
    const size_t row0 = (size_t)(wid * 1024 + g * 16 + m0);
    const int kbase = kb * 512 + q * 8;
#pragma unroll
    for (int ks = 0; ks < 16; ++ks) {
      const int k = kbase + ks * 32;
      const float* s0 = (k < 1024) ? (Wih + row0 * 1024 + k)
                                   : (Whh + row0 * 1024 + (k - 1024));
      const float* s1 = (k < 1024) ? (Wih + (row0 + 4096) * 1024 + k)
                                   : (Whh + (row0 + 4096) * 1024 + (k - 1024));
      float4 a = *(const float4*)s0, b = *(const float4*)(s0 + 4);
      w0[ks].x = (unsigned int)f2bf(a.x) | ((unsigned int)f2bf(a.y) << 16);
      w0[ks].y = (unsigned int)f2bf(a.z) | ((unsigned int)f2bf(a.w) << 16);
      w0[ks].z = (unsigned int)f2bf(b.x) | ((unsigned int)f2bf(b.y) << 16);
      w0[ks].w = (unsigned int)f2bf(b.z) | ((unsigned int)f2bf(b.w) << 16);
      float4 c = *(const float4*)s1, d = *(const float4*)(s1 + 4);
      w1[ks].x = (unsigned int)f2bf(c.x) | ((unsigned int)f2bf(c.y) << 16);
      w1[ks].y = (unsigned int)f2bf(c.z) | ((unsigned int)f2bf(c.w) << 16);
      w1[ks].z = (unsigned int)f2bf(d.x) | ((unsigned int)f2bf(d.y) << 16);
      w1[ks].w = (unsigned int)f2bf(d.z) | ((unsigned int)f2bf(d.w) << 16);
    }
  }

#pragma unroll 1
  for (int t = 0; t < 16; ++t) {
    cell_step<0>(t, w0, hmask, cmask, labels, out, ws, As, &lf);
    cell_step<1>(t, w1, hmask, cmask, labels, out, ws, As, &lf);
  }
}

// ---------------- finalize: loss ----------------
__global__ void fin_kernel(float* __restrict__ out, unsigned char* __restrict__ ws) {
  if (blockIdx.x == 0 && threadIdx.x == 0)
    out[524288] = *(float*)(ws + WS_SSE) * (1.0f / 524288.0f);
}

extern "C" void kernel_launch(void* const* d_in, const int* in_sizes, int n_in,
                              void* d_out, int out_size, void* d_ws, size_t ws_size,
                              hipStream_t stream) {
  (void)in_sizes; (void)n_in; (void)out_size; (void)ws_size;
  const float* x   = (const float*)d_in[0];
  const float* h0  = (const float*)d_in[1];
  const float* c0  = (const float*)d_in[2];
  const float* hm  = (const float*)d_in[3];
  const float* cm  = (const float*)d_in[4];
  const float* lb  = (const float*)d_in[5];
  const float* wih = (const float*)d_in[6];
  const float* whh = (const float*)d_in[7];
  const float* bi  = (const float*)d_in[8];
  const float* bh  = (const float*)d_in[9];
  float* out = (float*)d_out;
  unsigned char* ws = (unsigned char*)d_ws;

  prep_kernel<<<dim3(256), dim3(256), 0, stream>>>(x, h0, c0, bi, bh, ws);
  lstm_kernel<<<dim3(256), dim3(NTHR), 0, stream>>>(wih, whh, hm, cm, lb, out, ws);
  fin_kernel<<<dim3(1), dim3(64), 0, stream>>>(out, ws);
}

// Round 4
// 441.526 us; speedup vs baseline: 1.2556x; 1.1626x over previous
//
#include <hip/hip_runtime.h>

#define NTHR 256

typedef __bf16 bf16x8 __attribute__((ext_vector_type(8)));
typedef float  f32x4  __attribute__((ext_vector_type(4)));

__device__ __forceinline__ unsigned short f2bf(float f) {
  unsigned int u = __float_as_uint(f);
  return (unsigned short)((u + 0x7fffu + ((u >> 16) & 1u)) >> 16);  // RNE
}
__device__ __forceinline__ bf16x8 asbf(uint4 u) { return __builtin_bit_cast(bf16x8, u); }
__device__ __forceinline__ float sigf(float xv) { return 1.0f / (1.0f + __expf(-xv)); }

// --- cross-XCD primitives (proven in rounds 0/3) ---
template <typename T>
__device__ __forceinline__ T ald(const T* p) {
  return __hip_atomic_load(p, __ATOMIC_RELAXED, __HIP_MEMORY_SCOPE_AGENT);
}
__device__ __forceinline__ float2 ald2(const float* p) {
  unsigned long long v =
      __hip_atomic_load((const unsigned long long*)p, __ATOMIC_RELAXED, __HIP_MEMORY_SCOPE_AGENT);
  return __builtin_bit_cast(float2, v);
}
template <typename T>
__device__ __forceinline__ void xst(T* p, T v) {
  (void)__hip_atomic_exchange(p, v, __ATOMIC_RELAXED, __HIP_MEMORY_SCOPE_AGENT);
}
__device__ __forceinline__ unsigned long long pkf2(float a, float b) {
  float2 f = make_float2(a, b);
  return __builtin_bit_cast(unsigned long long, f);
}

// ws layout (bytes):
//   OUTB bf16 [2][32][1024]           parity ping-pong of cell input     131072
//   HBB  bf16 [2][2][32][1024]        [t-parity][layer] h for GEMM       262144
//   HST  f32  [2][32][1024]           fp32 h state                       262144
//   CST  f32  [2][32][1024]           fp32 c state                       262144
//   PS   f32  [2][64][4][4][32][16]   [ci-parity][g][kb][gate][m][c]    4194304
//   FLG  int  [32][64]                per-cell split-K completion flags     8192
//   CNT  int  [32]                    per-cell grid-barrier counters         128
//   BCB  f32  [2][4096]               combined bias                        32768
//   SSE  f32
#define WS_OUTB 0
#define WS_HBB  131072
#define WS_HST  (WS_HBB + 262144)
#define WS_CST  (WS_HST + 262144)
#define WS_PS   (WS_CST + 262144)
#define WS_FLG  (WS_PS + 4194304)
#define WS_CNT  (WS_FLG + 8192)
#define WS_BCB  (WS_CNT + 128)
#define WS_SSE  (WS_BCB + 32768)

// ---------------- prep: state init only ----------------
__global__ void prep_kernel(const float* __restrict__ x, const float* __restrict__ h0,
                            const float* __restrict__ c0,
                            const float* __restrict__ bih, const float* __restrict__ bhh,
                            unsigned char* __restrict__ ws)
{
  unsigned short* outb = (unsigned short*)(ws + WS_OUTB);
  unsigned short* hbb  = (unsigned short*)(ws + WS_HBB);
  float* hst = (float*)(ws + WS_HST);
  float* cst = (float*)(ws + WS_CST);
  int*   flg = (int*)(ws + WS_FLG);
  int*   cnt = (int*)(ws + WS_CNT);
  float* bcb = (float*)(ws + WS_BCB);
  float* sse = (float*)(ws + WS_SSE);

  int gid = blockIdx.x * blockDim.x + threadIdx.x;
  int stride = gridDim.x * blockDim.x;

  for (int i = gid; i < 32768; i += stride) outb[i] = f2bf(x[i]);   // parity 0 = x
  for (int i = gid; i < 65536; i += stride) {
    float h = h0[i];
    hbb[i] = f2bf(h);      // t-parity 0, both layers
    hst[i] = h;
    cst[i] = c0[i];
  }
  for (int i = gid; i < 8192; i += stride) bcb[i] = bih[i] + bhh[i];
  for (int i = gid; i < 2048; i += stride) flg[i] = 0;
  if (gid < 32) cnt[gid] = 0;
  if (gid == 0) *sse = 0.0f;
}

// ---------------- one cell inside the persistent kernel ----------------
template <int L>
__device__ __forceinline__ void cell_step(
    int t, const uint4 (&wreg)[16],
    const float* __restrict__ hmask, const float* __restrict__ cmask,
    const float* __restrict__ labels, float* __restrict__ out,
    unsigned char* __restrict__ ws, unsigned short* As, int* lfp)
{
  const int tid = threadIdx.x, bid = blockIdx.x;
  const int g = bid >> 2, kb = bid & 3;
  const int lane = tid & 63, wid = tid >> 6, q = lane >> 4, m0 = lane & 15;
  const int ci = t * 2 + L;

  unsigned short* outb = (unsigned short*)(ws + WS_OUTB);
  unsigned short* hbb  = (unsigned short*)(ws + WS_HBB);
  float* hst = (float*)(ws + WS_HST);
  float* cst = (float*)(ws + WS_CST);
  float* Psp = (float*)(ws + WS_PS) + (size_t)(ci & 1) * 524288;
  int*   flg = (int*)(ws + WS_FLG);
  int*   cnt = (int*)(ws + WS_CNT);
  const float* bcb = (const float*)(ws + WS_BCB);
  float* sse = (float*)(ws + WS_SSE);

  // pointwise geometry: 1 row (mr) x 2 adjacent cols (jg, jg+1) per thread
  const int mr = tid >> 3, c2 = tid & 7;
  const int jg = g * 16 + c2 * 2;

  // --- read-only prefetch (immutable; plain cached loads; issued before the
  //     spin so HBM latency hides under it) ---
  const int mbase = ci * 32768 + mr * 1024 + jg;
  float2 hm = *(const float2*)&hmask[mbase];
  float2 cm = *(const float2*)&cmask[mbase];
  float2 lb = make_float2(0.f, 0.f);
  if (L == 1) lb = *(const float2*)&labels[(mr * 16 + t) * 1024 + jg];
  float2 bv[4];
#pragma unroll
  for (int gt = 0; gt < 4; ++gt)
    bv[gt] = *(const float2*)&bcb[L * 4096 + gt * 1024 + jg];  // immutable after prep

  // --- dependency-skewed grid barrier:
  //     kb<2 reads outb (written at ci-1)  -> wait cnt[ci-1]
  //     kb>=2 reads hbb/state (from ci-2)  -> wait cnt[ci-2], runs a cell early
  const int need = ci - 1 - (kb >> 1);
  if (need >= 0) {
    if (tid == 0) {
      while (ald(&cnt[need]) < 64) __builtin_amdgcn_s_sleep(1);
    }
    __syncthreads();
  }

  // --- A staging: 32 rows x 512 bf16 slice, 4096 x 8B device-coherent loads ---
  // chunk u (0..4095): row = u>>7 (0..31), c4 = u&127 (4-short units)
  const unsigned short* asrc = (kb < 2)
      ? (outb + L * 32768 + kb * 512)
      : (hbb + ((t & 1) * 2 + L) * 32768 + (kb - 2) * 512);
  unsigned long long av[16];
#pragma unroll
  for (int it = 0; it < 16; ++it) {
    const int u = it * 256 + tid, row = u >> 7, c4 = u & 127;
    av[it] = ald((const unsigned long long*)(asrc + row * 1024 + c4 * 4));
  }
  // fp32 state prefetch (written at ci-2; both wait targets cover it)
  const int sidx = L * 32768 + mr * 1024 + jg;
  float cp0 = ald(&cst[sidx]), cp1 = ald(&cst[sidx + 1]);
  float hp0 = ald(&hst[sidx]), hp1 = ald(&hst[sidx + 1]);
#pragma unroll
  for (int it = 0; it < 16; ++it) {
    const int u = it * 256 + tid, row = u >> 7, c4 = u & 127;
    *(unsigned long long*)&As[row * 520 + c4 * 4] = av[it];
  }
  __syncthreads();

  // --- MFMA: B operand resident in registers, A from LDS ---
  f32x4 acc0 = {0.f, 0.f, 0.f, 0.f}, acc1 = {0.f, 0.f, 0.f, 0.f};
#pragma unroll
  for (int ks = 0; ks < 16; ++ks) {
    const int kl = ks * 32 + q * 8;
    bf16x8 a0 = asbf(*(const uint4*)&As[m0 * 520 + kl]);
    bf16x8 a1 = asbf(*(const uint4*)&As[(m0 + 16) * 520 + kl]);
    bf16x8 b  = asbf(wreg[ks]);
    acc0 = __builtin_amdgcn_mfma_f32_16x16x32_bf16(a0, b, acc0, 0, 0, 0);
    acc1 = __builtin_amdgcn_mfma_f32_16x16x32_bf16(a1, b, acc1, 0, 0, 0);
  }

  // --- split-K partials: disjoint slots, transposed [gate][m][c] layout ---
  // C/D frag: c = lane&15, m = q*4+i (+16). Ps row stride over m is 16 floats.
  float* pq = Psp + (size_t)(((g * 4 + kb) * 4 + wid) * 32) * 16 + m0;
#pragma unroll
  for (int i = 0; i < 4; ++i) {
    xst(pq + (q * 4 + i) * 16,        acc0[i]);
    xst(pq + (q * 4 + i + 16) * 16,   acc1[i]);
  }

  __syncthreads();                    // vmcnt(0): exchanges complete at coherence point
  if (tid == 0)
    *lfp = __hip_atomic_fetch_add(&flg[ci * 64 + g], 1, __ATOMIC_RELAXED, __HIP_MEMORY_SCOPE_AGENT);
  __syncthreads();
  if (*lfp != 3) return;              // not the last K-quarter of this group

  // --- pointwise (last-arriving block of this column group) ---
  const float* pbase = Psp + (size_t)g * 8192;   // [kb][gate][m][c]
  float gs0[4], gs1[4];
#pragma unroll
  for (int gt = 0; gt < 4; ++gt) {
    float s0 = bv[gt].x, s1 = bv[gt].y;
#pragma unroll
    for (int k2 = 0; k2 < 4; ++k2) {
      float2 v = ald2(pbase + ((size_t)(k2 * 4 + gt) * 32 + mr) * 16 + c2 * 2);
      s0 += v.x; s1 += v.y;
    }
    gs0[gt] = s0; gs1[gt] = s1;
  }

  float i0 = sigf(gs0[0]), f0 = sigf(gs0[1]), g0 = tanhf(gs0[2]), o0 = sigf(gs0[3]);
  float i1 = sigf(gs1[0]), f1 = sigf(gs1[1]), g1 = tanhf(gs1[2]), o1 = sigf(gs1[3]);
  float cc0 = f0 * cp0 + i0 * g0, cc1 = f1 * cp1 + i1 * g1;
  float hc0 = o0 * tanhf(cc0),    hc1 = o1 * tanhf(cc1);
  float hn0 = hm.x * hp0 + (1.0f - hm.x) * hc0;
  float hn1 = hm.y * hp1 + (1.0f - hm.y) * hc1;
  float cn0 = cm.x * cp0 + (1.0f - cm.x) * cc0;
  float cn1 = cm.y * cp1 + (1.0f - cm.y) * cc1;

  xst((unsigned long long*)&cst[sidx], pkf2(cn0, cn1));
  xst((unsigned long long*)&hst[sidx], pkf2(hn0, hn1));
  const unsigned int hb = (unsigned int)f2bf(hn0) | ((unsigned int)f2bf(hn1) << 16);
  xst((unsigned int*)&outb[(L ^ 1) * 32768 + mr * 1024 + jg], hb);
  xst((unsigned int*)&hbb[(((t + 1) & 1) * 2 + L) * 32768 + mr * 1024 + jg], hb);

  if (L == 1) {
    *(float2*)&out[(mr * 16 + t) * 1024 + jg] = make_float2(hn0, hn1);  // flushed at kernel end
    float d0 = hn0 - lb.x, d1 = hn1 - lb.y;
    float s = d0 * d0 + d1 * d1;
#pragma unroll
    for (int off = 32; off > 0; off >>= 1) s += __shfl_down(s, off);
    if (lane == 0) atomicAdd(sse, s);
  }

  __syncthreads();                    // vmcnt(0): pointwise publishes complete
  if (tid == 0)
    __hip_atomic_fetch_add(&cnt[ci], 1, __ATOMIC_RELAXED, __HIP_MEMORY_SCOPE_AGENT);
}

// ---------------- persistent kernel: weights in registers, 32 cells in-kernel ----
// grid = 256 blocks (1/CU resident by construction).
__global__ void __launch_bounds__(NTHR, 1)
lstm_kernel(const float* __restrict__ Wih, const float* __restrict__ Whh,
            const float* __restrict__ hmask, const float* __restrict__ cmask,
            const float* __restrict__ labels, float* __restrict__ out,
            unsigned char* __restrict__ ws)
{
  const int tid = threadIdx.x, bid = blockIdx.x;
  const int g = bid >> 2, kb = bid & 3;
  const int wid = tid >> 6, q = (tid & 63) >> 4, m0 = tid & 15;

  __shared__ __align__(16) unsigned short As[32 * 520];
  __shared__ int lf;

  // ---- one-time: fp32 weights -> bf16 registers, both layers (128 VGPRs) ----
  // row (layer l) = l*4096 + wid*1024 + g*16 + m0 ; K-concat col = kb*512 + q*8 + ks*32
  uint4 w0[16], w1[16];
  {
    const size_t row0 = (size_t)(wid * 1024 + g * 16 + m0);
    const int kbase = kb * 512 + q * 8;
#pragma unroll
    for (int ks = 0; ks < 16; ++ks) {
      const int k = kbase + ks * 32;
      const float* s0 = (k < 1024) ? (Wih + row0 * 1024 + k)
                                   : (Whh + row0 * 1024 + (k - 1024));
      const float* s1 = (k < 1024) ? (Wih + (row0 + 4096) * 1024 + k)
                                   : (Whh + (row0 + 4096) * 1024 + (k - 1024));
      float4 a = *(const float4*)s0, b = *(const float4*)(s0 + 4);
      w0[ks].x = (unsigned int)f2bf(a.x) | ((unsigned int)f2bf(a.y) << 16);
      w0[ks].y = (unsigned int)f2bf(a.z) | ((unsigned int)f2bf(a.w) << 16);
      w0[ks].z = (unsigned int)f2bf(b.x) | ((unsigned int)f2bf(b.y) << 16);
      w0[ks].w = (unsigned int)f2bf(b.z) | ((unsigned int)f2bf(b.w) << 16);
      float4 c = *(const float4*)s1, d = *(const float4*)(s1 + 4);
      w1[ks].x = (unsigned int)f2bf(c.x) | ((unsigned int)f2bf(c.y) << 16);
      w1[ks].y = (unsigned int)f2bf(c.z) | ((unsigned int)f2bf(c.w) << 16);
      w1[ks].z = (unsigned int)f2bf(d.x) | ((unsigned int)f2bf(d.y) << 16);
      w1[ks].w = (unsigned int)f2bf(d.z) | ((unsigned int)f2bf(d.w) << 16);
    }
  }

#pragma unroll 1
  for (int t = 0; t < 16; ++t) {
    cell_step<0>(t, w0, hmask, cmask, labels, out, ws, As, &lf);
    cell_step<1>(t, w1, hmask, cmask, labels, out, ws, As, &lf);
  }
}

// ---------------- finalize: loss ----------------
__global__ void fin_kernel(float* __restrict__ out, unsigned char* __restrict__ ws) {
  if (blockIdx.x == 0 && threadIdx.x == 0)
    out[524288] = *(float*)(ws + WS_SSE) * (1.0f / 524288.0f);
}

extern "C" void kernel_launch(void* const* d_in, const int* in_sizes, int n_in,
                              void* d_out, int out_size, void* d_ws, size_t ws_size,
                              hipStream_t stream) {
  (void)in_sizes; (void)n_in; (void)out_size; (void)ws_size;
  const float* x   = (const float*)d_in[0];
  const float* h0  = (const float*)d_in[1];
  const float* c0  = (const float*)d_in[2];
  const float* hm  = (const float*)d_in[3];
  const float* cm  = (const float*)d_in[4];
  const float* lb  = (const float*)d_in[5];
  const float* wih = (const float*)d_in[6];
  const float* whh = (const float*)d_in[7];
  const float* bi  = (const float*)d_in[8];
  const float* bh  = (const float*)d_in[9];
  float* out = (float*)d_out;
  unsigned char* ws = (unsigned char*)d_ws;

  prep_kernel<<<dim3(256), dim3(256), 0, stream>>>(x, h0, c0, bi, bh, ws);
  lstm_kernel<<<dim3(256), dim3(NTHR), 0, stream>>>(wih, whh, hm, cm, lb, out, ws);
  fin_kernel<<<dim3(1), dim3(64), 0, stream>>>(out, ws);
}